// Round 17
// baseline (163.413 us; speedup 1.0000x reference)
//
#include <hip/hip_runtime.h>

#define B_  2
#define S_  2048
#define E_  1024
#define H_  16
#define D_  64
#define NGLOB 2
#define NRAND 3
#define WIN 3

typedef __bf16 bf16x8 __attribute__((ext_vector_type(8)));
typedef float  f32x4  __attribute__((ext_vector_type(4)));

__device__ __forceinline__ unsigned short f2bf(float f) {
    unsigned u = __builtin_bit_cast(unsigned, f);
    unsigned r = u + 0x7FFFu + ((u >> 16) & 1u);   // RNE
    return (unsigned short)(r >> 16);
}
__device__ __forceinline__ float bf2f(unsigned short u) {
    return __builtin_bit_cast(float, (unsigned)u << 16);
}

// async global->LDS 16B DMA. LDS dest is wave-uniform base + lane*16.
__device__ __forceinline__ void g2l16(const unsigned short* g, unsigned short* l) {
    __builtin_amdgcn_global_load_lds(
        (const __attribute__((address_space(1))) unsigned*)g,
        (__attribute__((address_space(3))) unsigned*)l, 16, 0, 0);
}

// ---------------- fused fp32 -> bf16 conversion for x + 4 weights ----------------
__global__ __launch_bounds__(256)
void convert_all(const float* __restrict__ x,  const float* __restrict__ qw,
                 const float* __restrict__ kw, const float* __restrict__ vw,
                 const float* __restrict__ ow,
                 unsigned short* __restrict__ xb, unsigned short* __restrict__ wqkv,
                 unsigned short* __restrict__ wo) {
    const int XN = (B_ * S_ * E_) / 4;      // 1048576
    const int WN = (E_ * E_) / 4;           // 262144
    int i = blockIdx.x * blockDim.x + threadIdx.x;
    int r, loc;
    if (i < XN) { r = 0; loc = i; }
    else        { int j = i - XN; r = 1 + (j >> 18); loc = j & (WN - 1); }
    const float* src = r == 0 ? x : r == 1 ? qw : r == 2 ? kw : r == 3 ? vw : ow;
    float4 f = ((const float4*)src)[loc];
    ushort4 u;
    u.x = f2bf(f.x); u.y = f2bf(f.y); u.z = f2bf(f.z); u.w = f2bf(f.w);
    ushort4* dst = r == 0 ? (ushort4*)xb : r == 4 ? (ushort4*)wo
                 : (ushort4*)wqkv + (size_t)(r - 1) * WN;
    dst[loc] = u;
}

// ---------------- QKV GEMM: BK=64, XOR-swizzled LDS, 4 blocks/CU ------------------
__global__ __launch_bounds__(256, 4)
void gemm_qkv(const unsigned short* __restrict__ A,  // [M][K] bf16
              const unsigned short* __restrict__ W,  // [N][K] bf16
              const float* __restrict__ b0, const float* __restrict__ b1,
              const float* __restrict__ b2,
              unsigned short* __restrict__ Cb, int M, int N, int K) {
    __shared__ unsigned short sA[128 * 64];   // 16 KB
    __shared__ unsigned short sB[128 * 64];   // 16 KB
    const int t = threadIdx.x;
    const int lane = t & 63;
    const int wave = t >> 6;
    const int wm = wave >> 1, wn = wave & 1;
    const int lq = lane >> 4;
    const int lr = lane & 15;
    const int bm = blockIdx.x * 128;
    const int bn = blockIdx.y * 128;

    f32x4 acc[4][4] = {};

    for (int k0 = 0; k0 < K; k0 += 64) {
        const unsigned short* Abase = A + (size_t)bm * K + k0;
        const unsigned short* Wbase = W + (size_t)bn * K + k0;
        #pragma unroll
        for (int j = 0; j < 4; ++j) {             // 1024 chunks each
            int c = j * 256 + t;
            int row = c >> 3, cc = c & 7;
            int gcol = ((cc ^ (row & 7)) << 3);   // swizzled source col
            int dst = j * 2048 + wave * 512;      // wave-uniform elem offset
            g2l16(Abase + (size_t)row * K + gcol, sA + dst);
            g2l16(Wbase + (size_t)row * K + gcol, sB + dst);
        }
        __syncthreads();

        #pragma unroll
        for (int ks = 0; ks < 2; ++ks) {
            const int sw = (((ks << 2) + lq) ^ (lr & 7)) << 3;
            bf16x8 af[4], bfr[4];
            #pragma unroll
            for (int i = 0; i < 4; ++i)
                af[i] = *(const bf16x8*)&sA[(wm * 64 + i * 16 + lr) * 64 + sw];
            #pragma unroll
            for (int j = 0; j < 4; ++j)
                bfr[j] = *(const bf16x8*)&sB[(wn * 64 + j * 16 + lr) * 64 + sw];
            #pragma unroll
            for (int i = 0; i < 4; ++i)
                #pragma unroll
                for (int j = 0; j < 4; ++j)
                    acc[i][j] = __builtin_amdgcn_mfma_f32_16x16x32_bf16(af[i], bfr[j], acc[i][j], 0, 0, 0);
        }
        __syncthreads();
    }

    #pragma unroll
    for (int i = 0; i < 4; ++i) {
        int row0 = bm + wm * 64 + i * 16 + lq * 4;
        #pragma unroll
        for (int j = 0; j < 4; ++j) {
            int col = bn + wn * 64 + j * 16 + lr;
            const float* bp = col < E_ ? b0 : (col < 2 * E_ ? b1 : b2);
            float bv = bp[col & (E_ - 1)];
            #pragma unroll
            for (int r = 0; r < 4; ++r)
                Cb[(size_t)(row0 + r) * N + col] = f2bf(acc[i][j][r] + bv);
        }
    }
}

// ---------------- O GEMM: 128x128 tile, fused global-row merge --------------------
__global__ __launch_bounds__(256, 3)
void gemm_o(unsigned short* A,                      // attn (read + global-row write)
            const unsigned short* __restrict__ W,   // [N][K] bf16 (wo)
            const float* __restrict__ bias,
            const float* __restrict__ gaccp, const float* __restrict__ gms,
            float* __restrict__ Cf, int M, int N, int K) {
    __shared__ unsigned short sA[128 * 64];   // 16 KB
    __shared__ unsigned short sB[128 * 64];   // 16 KB
    const int t = threadIdx.x;
    const int lane = t & 63;
    const int wave = t >> 6;
    const int wm = wave >> 1, wn = wave & 1;
    const int lq = lane >> 4;
    const int lr = lane & 15;
    const int bm = blockIdx.x * 128;
    const int bn = blockIdx.y * 128;

    // ---- fused gattn_fin for this tile's global rows ----
    if (blockIdx.x == 0 || blockIdx.x == 16) {
        int b = blockIdx.x >> 4;
        #pragma unroll
        for (int r = 0; r < 8; ++r) {
            int oid = r * 256 + t;              // 0..2047 : i2*1024 + col
            int i2 = oid >> 10, col = oid & 1023;
            int h = col >> 6, d = col & 63;
            int tup = b * 32 + i2 * 16 + h;
            float Mx = -1e30f;
            #pragma unroll
            for (int c = 0; c < 8; ++c) Mx = fmaxf(Mx, gms[(tup * 8 + c) * 2]);
            float den = 0.f, num = 0.f;
            #pragma unroll
            for (int c = 0; c < 8; ++c) {
                float f = __expf(gms[(tup * 8 + c) * 2] - Mx);
                den += gms[(tup * 8 + c) * 2 + 1] * f;
                num += gaccp[(size_t)(tup * 8 + c) * D_ + d] * f;
            }
            A[(size_t)(b * S_ + i2) * E_ + col] = f2bf(num / den);
        }
        asm volatile("s_waitcnt vmcnt(0)" ::: "memory");
    }
    __syncthreads();

    f32x4 acc[4][4] = {};

    for (int k0 = 0; k0 < K; k0 += 64) {
        const unsigned short* Abase = A + (size_t)bm * K + k0;
        const unsigned short* Wbase = W + (size_t)bn * K + k0;
        #pragma unroll
        for (int j = 0; j < 4; ++j) {
            int c = j * 256 + t;
            int row = c >> 3, cc = c & 7;
            int gcol = ((cc ^ (row & 7)) << 3);
            int dst = j * 2048 + wave * 512;
            g2l16(Abase + (size_t)row * K + gcol, sA + dst);
            g2l16(Wbase + (size_t)row * K + gcol, sB + dst);
        }
        __syncthreads();

        #pragma unroll
        for (int ks = 0; ks < 2; ++ks) {
            const int sw = (((ks << 2) + lq) ^ (lr & 7)) << 3;
            bf16x8 af[4], bfr[4];
            #pragma unroll
            for (int i = 0; i < 4; ++i)
                af[i] = *(const bf16x8*)&sA[(wm * 64 + i * 16 + lr) * 64 + sw];
            #pragma unroll
            for (int j = 0; j < 4; ++j)
                bfr[j] = *(const bf16x8*)&sB[(wn * 64 + j * 16 + lr) * 64 + sw];
            #pragma unroll
            for (int i = 0; i < 4; ++i)
                #pragma unroll
                for (int j = 0; j < 4; ++j)
                    acc[i][j] = __builtin_amdgcn_mfma_f32_16x16x32_bf16(af[i], bfr[j], acc[i][j], 0, 0, 0);
        }
        __syncthreads();
    }

    #pragma unroll
    for (int i = 0; i < 4; ++i) {
        int row0 = bm + wm * 64 + i * 16 + lq * 4;
        #pragma unroll
        for (int j = 0; j < 4; ++j) {
            int col = bn + wn * 64 + j * 16 + lr;
            float bv = bias[col];
            #pragma unroll
            for (int r = 0; r < 4; ++r)
                Cf[(size_t)(row0 + r) * N + col] = acc[i][j][r] + bv;
        }
    }
}

// ---------------- fused attn: 8-wave blocks, halved serial chains (R17) -----------
// Global blocks [0,512): wave w covers 32 keys (4 iters of 8) — was 64/8. 8-wave
// LDS flash merge to gms/gaccp (same interface). Sparse blocks [512,1536): 4 rows x
// 2 waves/row; each wave streams 6 of the 12 candidates (all K+V loads fit in
// flight ~ one latency round), per-head flash partials merged through padded LDS
// ([64][17] stride: 2-way bank aliasing = free). Same math as R13.
__global__ __launch_bounds__(512)
void attn_fused(const unsigned short* __restrict__ qkv,
                const int* __restrict__ rnd,
                float* __restrict__ gaccp, float* __restrict__ gms,
                unsigned short* __restrict__ attn) {
    const int NB = B_ * (S_ - 2);     // 4092
    int t = threadIdx.x;
    int w = t >> 6, l = t & 63;

    if (blockIdx.x < 512) {
        // ---- one (tuple, key-chunk) per block; 8 waves x 32 keys ----
        int tup = blockIdx.x >> 3, seg = blockIdx.x & 7;
        int b = tup >> 5, i = (tup >> 4) & 1, h = tup & 15;
        __shared__ float redm[8], reds[8];
        __shared__ float ov[8][D_];

        const bf16x8* qp = (const bf16x8*)(qkv + (size_t)(b * S_ + i) * 3072 + h * D_);
        bf16x8 qv = qp[l & 7];
        float qreg[8];
        #pragma unroll
        for (int j = 0; j < 8; ++j) qreg[j] = (float)qv[j];

        const int key0 = seg * 256 + w * 32;
        const int ksb = l >> 3, dg = l & 7;
        float mM = -1e30f, ssum = 0.f;
        float o[8] = {};
        #pragma unroll
        for (int it = 0; it < 4; ++it) {
            int key = key0 + it * 8 + ksb;
            const unsigned short* kr =
                qkv + (size_t)(b * S_ + key) * 3072 + E_ + h * D_ + dg * 8;
            bf16x8 kv = *(const bf16x8*)kr;          // K chunk
            bf16x8 vv = *(const bf16x8*)(kr + E_);   // V chunk
            float s = 0.f;
            #pragma unroll
            for (int j = 0; j < 8; ++j) s += qreg[j] * (float)kv[j];
            s += __shfl_xor(s, 1);
            s += __shfl_xor(s, 2);
            s += __shfl_xor(s, 4);
            s *= 0.125f;
            float m_it = s;
            m_it = fmaxf(m_it, __shfl_xor(m_it, 8));
            m_it = fmaxf(m_it, __shfl_xor(m_it, 16));
            m_it = fmaxf(m_it, __shfl_xor(m_it, 32));
            if (m_it > mM) {                         // wave-uniform
                float r = __expf(mM - m_it);
                ssum *= r;
                #pragma unroll
                for (int e2 = 0; e2 < 8; ++e2) o[e2] *= r;
                mM = m_it;
            }
            float e = __expf(s - mM);
            ssum += e;
            #pragma unroll
            for (int e2 = 0; e2 < 8; ++e2) o[e2] += e * (float)vv[e2];
        }
        // reduce over key-subs (masks vary ksb, keep dg)
        #pragma unroll
        for (int mask = 8; mask <= 32; mask <<= 1) {
            ssum += __shfl_xor(ssum, mask);
            #pragma unroll
            for (int e2 = 0; e2 < 8; ++e2) o[e2] += __shfl_xor(o[e2], mask);
        }
        if (l == 0) { redm[w] = mM; reds[w] = ssum; }
        if (ksb == 0)
            #pragma unroll
            for (int e2 = 0; e2 < 8; ++e2) ov[w][dg * 8 + e2] = o[e2];
        __syncthreads();
        if (w == 0) {
            float M = -1e30f;
            #pragma unroll
            for (int ww = 0; ww < 8; ++ww) M = fmaxf(M, redm[ww]);
            float num = 0.f, den = 0.f;
            #pragma unroll
            for (int ww = 0; ww < 8; ++ww) {
                float f = __expf(redm[ww] - M);
                num += ov[ww][l] * f;
                den += reds[ww] * f;
            }
            gaccp[((size_t)tup * 8 + seg) * D_ + l] = num;
            if (l == 0) {
                gms[(tup * 8 + seg) * 2]     = M;
                gms[(tup * 8 + seg) * 2 + 1] = den;
            }
        }
        return;
    }

    // ---- sparse rows: 4 rows/block, 2 waves per row (6 candidates each) ----
    int bb = blockIdx.x - 512;                        // [0,1024)
    int bidx = (bb & 7) * 128 + (bb >> 3);            // XCD swizzle
    int r = w >> 1, half = w & 1;
    int row = bidx * 4 + r;
    bool valid = row < NB;
    int b = row / (S_ - 2);
    int i = row % (S_ - 2) + 2;
    if (!valid) { b = 0; i = 2; }

    __shared__ int   cols_s[4][12];
    __shared__ int   ncol_sh[4];
    __shared__ float mh[4][2][16], sh[4][2][16];
    __shared__ float oh[4][2][64][17];                // padded: stride 17 words

    const bf16x8* qp = (const bf16x8*)(qkv + (size_t)(b * S_ + i) * 3072);
    bf16x8 q0 = qp[l * 2], q1 = qp[l * 2 + 1];
    float qreg[16];
    #pragma unroll
    for (int j = 0; j < 8; ++j) { qreg[j] = (float)q0[j]; qreg[8 + j] = (float)q1[j]; }

    if (half == 0 && l == 0) {
        int* cols = cols_s[r];
        int n = 0;
        cols[n++] = 0; cols[n++] = 1;
        int lo = i - WIN; if (lo < NGLOB) lo = NGLOB;
        int hi = i + WIN; if (hi > S_ - 1) hi = S_ - 1;
        for (int j = lo; j <= hi; ++j) cols[n++] = j;
        for (int q = 0; q < NRAND; ++q) {
            int c = rnd[i * NRAND + q];
            bool dup = false;
            for (int p = 0; p < n; ++p) dup = dup || (cols[p] == c);
            if (!dup) cols[n++] = c;
        }
        ncol_sh[r] = n;
        for (int q = n; q < 12; ++q) cols[q] = 0;
    }
    __syncthreads();
    const int n = ncol_sh[r];

    // per-wave streaming flash over 6 candidates [half*6, half*6+6)
    float mM = -1e30f, ssum = 0.f;
    float o[16] = {};
    #pragma unroll
    for (int j6 = 0; j6 < 6; ++j6) {
        int c = half * 6 + j6;
        const unsigned short* base = qkv + (size_t)(b * S_ + cols_s[r][c]) * 3072 + E_;
        const bf16x8* kp = (const bf16x8*)base;
        bf16x8 k0 = kp[l * 2], k1 = kp[l * 2 + 1];
        const bf16x8* vp = (const bf16x8*)(base + E_);
        bf16x8 v0 = vp[l * 2], v1 = vp[l * 2 + 1];
        float s = 0.f;
        #pragma unroll
        for (int j = 0; j < 8; ++j) s += qreg[j] * (float)k0[j] + qreg[8 + j] * (float)k1[j];
        s += __shfl_xor(s, 1);
        s += __shfl_xor(s, 2);
        bool ok = (c < n);
        s = ok ? s * 0.125f : -1e30f;
        if (s > mM) {                         // group-uniform (4-lane group = one head)
            float rr = __expf(mM - s);
            ssum *= rr;
            #pragma unroll
            for (int j = 0; j < 16; ++j) o[j] *= rr;
            mM = s;
        }
        float e = ok ? __expf(s - mM) : 0.f;  // explicit 0 for masked (handles all-masked half)
        ssum += e;
        #pragma unroll
        for (int j = 0; j < 8; ++j) { o[j] += e * (float)v0[j]; o[8 + j] += e * (float)v1[j]; }
    }

    // publish per-wave partials
    if ((l & 3) == 0) { mh[r][half][l >> 2] = mM; sh[r][half][l >> 2] = ssum; }
    #pragma unroll
    for (int j = 0; j < 16; ++j) oh[r][half][l][j] = o[j];
    __syncthreads();

    // half==0 waves combine and write
    if (half == 0 && valid) {
        int h4 = l >> 2;
        float m0 = mh[r][0][h4], m1 = mh[r][1][h4];
        float M = fmaxf(m0, m1);
        float f0 = __expf(m0 - M), f1 = __expf(m1 - M);
        float den = sh[r][0][h4] * f0 + sh[r][1][h4] * f1;
        float inv = 1.f / den;
        float oc[16];
        #pragma unroll
        for (int j = 0; j < 16; ++j)
            oc[j] = (o[j] * f0 + oh[r][1][l][j] * f1) * inv;

        ushort4 u0, u1, u2, u3;
        u0.x = f2bf(oc[0]);  u0.y = f2bf(oc[1]);  u0.z = f2bf(oc[2]);  u0.w = f2bf(oc[3]);
        u1.x = f2bf(oc[4]);  u1.y = f2bf(oc[5]);  u1.z = f2bf(oc[6]);  u1.w = f2bf(oc[7]);
        u2.x = f2bf(oc[8]);  u2.y = f2bf(oc[9]);  u2.z = f2bf(oc[10]); u2.w = f2bf(oc[11]);
        u3.x = f2bf(oc[12]); u3.y = f2bf(oc[13]); u3.z = f2bf(oc[14]); u3.w = f2bf(oc[15]);
        ushort4* op = (ushort4*)(attn + (size_t)(b * S_ + i) * E_ + l * 16);
        op[0] = u0; op[1] = u1; op[2] = u2; op[3] = u3;
    }
}

extern "C" void kernel_launch(void* const* d_in, const int* in_sizes, int n_in,
                              void* d_out, int out_size, void* d_ws, size_t ws_size,
                              hipStream_t stream) {
    const float* x   = (const float*)d_in[0];
    const int*   rnd = (const int*)d_in[1];
    const float* qw  = (const float*)d_in[2];
    const float* qb  = (const float*)d_in[3];
    const float* kw  = (const float*)d_in[4];
    const float* kb  = (const float*)d_in[5];
    const float* vw  = (const float*)d_in[6];
    const float* vb  = (const float*)d_in[7];
    const float* ow  = (const float*)d_in[8];
    const float* ob  = (const float*)d_in[9];
    float* out = (float*)d_out;

    char* ws = (char*)d_ws;
    unsigned short* xb    = (unsigned short*)(ws);                       // 8 MB (dead after QKV GEMM)
    unsigned short* wqkv  = (unsigned short*)(ws + 8388608);             // 6 MB
    unsigned short* wo    = (unsigned short*)(ws + 14680064);            // 2 MB
    unsigned short* qkv   = (unsigned short*)(ws + 16777216);            // 24 MB
    unsigned short* attn  = (unsigned short*)(ws + 41943040);            // 8 MB
    float*          gaccp = (float*)(ws);                                // 128 KB (overlaps dead xb)
    float*          gms   = (float*)(ws + 131072);                       // 4 KB

    const int M = B_ * S_;   // 4096

    {
        int total4 = (M * E_ + 4 * E_ * E_) / 4;
        convert_all<<<total4 / 256, 256, 0, stream>>>(x, qw, kw, vw, ow, xb, wqkv, wo);
    }

    // QKV GEMM: [4096][3072] bf16, BK=64 swizzled, 4 blocks/CU
    {
        dim3 grid(M / 128, 3 * E_ / 128);
        gemm_qkv<<<grid, 256, 0, stream>>>(xb, wqkv, qb, kb, vb, qkv, M, 3 * E_, E_);
    }

    // global chunks (512) + sparse rows (1024), 8-wave blocks, halved chains
    attn_fused<<<512 + 1024, 512, 0, stream>>>(qkv, rnd, gaccp, gms, attn);

    // O GEMM -> fp32 out, 128x128 tile, fused global-row merge (no fin dispatch)
    {
        dim3 grid(M / 128, E_ / 128);
        gemm_o<<<grid, 256, 0, stream>>>(attn, wo, ob, gaccp, gms, out, M, E_, E_);
    }
}